// Round 1
// baseline (1950.805 us; speedup 1.0000x reference)
//
#include <hip/hip_runtime.h>
#include <hip/hip_bf16.h>
#include <math.h>

// Problem constants
#define DIMD   768
#define HEADS  16
#define HD     48
#define SEQ    2048
#define BATCH  4
#define NTOK   (BATCH * SEQ)     // 8192
#define QKVD   (3 * DIMD)        // 2304
#define ATT_SCALE 0.14433756729740643f   // 1/sqrt(48)

// ---------------------------------------------------------------------------
// Generic fp32 tiled GEMM: C[M,N] = A[M,K] @ B[K,N] (+ bias[N] if non-null)
// BM=BN=64, BK=16, 256 threads, 4x4 register tile per thread.
// ---------------------------------------------------------------------------
#define BM 64
#define BN 64
#define BK 16

__global__ __launch_bounds__(256) void gemm_f32(
    const float* __restrict__ A, const float* __restrict__ B,
    const float* __restrict__ bias, float* __restrict__ C,
    int M, int N, int K) {
  __shared__ float As[BK][BM];   // A^T tile: As[k][m]
  __shared__ float Bs[BK][BN];   // Bs[k][n]

  const int t  = threadIdx.x;
  const int tx = t & 15;         // n-quad: cols tx*4..tx*4+3
  const int ty = t >> 4;         // m-quad: rows ty*4..ty*4+3
  const int m0 = blockIdx.y * BM;
  const int n0 = blockIdx.x * BN;

  // loader assignments
  const int arow = t >> 2;          // 0..63
  const int acol = (t & 3) << 2;    // 0,4,8,12
  const int brow = t >> 4;          // 0..15
  const int bcol = (t & 15) << 2;   // 0..60

  float acc[4][4] = {{0.f, 0.f, 0.f, 0.f}, {0.f, 0.f, 0.f, 0.f},
                     {0.f, 0.f, 0.f, 0.f}, {0.f, 0.f, 0.f, 0.f}};

  for (int k0 = 0; k0 < K; k0 += BK) {
    __syncthreads();   // protect LDS from previous iteration's readers
    float4 av = *(const float4*)(A + (size_t)(m0 + arow) * K + (k0 + acol));
    float4 bv = *(const float4*)(B + (size_t)(k0 + brow) * N + (n0 + bcol));
    As[acol + 0][arow] = av.x;
    As[acol + 1][arow] = av.y;
    As[acol + 2][arow] = av.z;
    As[acol + 3][arow] = av.w;
    *(float4*)&Bs[brow][bcol] = bv;
    __syncthreads();

#pragma unroll
    for (int kk = 0; kk < BK; ++kk) {
      float4 a = *(const float4*)&As[kk][ty << 2];
      float4 b = *(const float4*)&Bs[kk][tx << 2];
      float ar[4] = {a.x, a.y, a.z, a.w};
      float br[4] = {b.x, b.y, b.z, b.w};
#pragma unroll
      for (int i = 0; i < 4; ++i)
#pragma unroll
        for (int j = 0; j < 4; ++j)
          acc[i][j] = fmaf(ar[i], br[j], acc[i][j]);
    }
  }

  const int colg = n0 + (tx << 2);
  float4 bb = {0.f, 0.f, 0.f, 0.f};
  if (bias) bb = *(const float4*)(bias + colg);
#pragma unroll
  for (int i = 0; i < 4; ++i) {
    size_t row = (size_t)(m0 + (ty << 2) + i);
    float4 v;
    v.x = acc[i][0] + bb.x;
    v.y = acc[i][1] + bb.y;
    v.z = acc[i][2] + bb.z;
    v.w = acc[i][3] + bb.w;
    *(float4*)(C + row * N + colg) = v;
  }
}

// ---------------------------------------------------------------------------
// Flash-style fp32 attention.
// QKV layout: [B, S, 3*DIMD] (raw qkv GEMM output).
// One block = one (b, h, 64-row q-tile). 256 threads.
// Thread (g = t>>4, c = t&15): score tile rows 4g..4g+3, cols 4c..4c+3;
// output dims e = 3c..3c+2 for its 4 rows.
// ---------------------------------------------------------------------------
#define ATQ 64
#define ATK 64

__global__ __launch_bounds__(256) void attn_f32(const float* __restrict__ QKV,
                                                float* __restrict__ Aout) {
  const int bh = blockIdx.y;
  const int b  = bh >> 4;
  const int h  = bh & 15;
  const int qt = blockIdx.x;

  const float* qbase = QKV + (size_t)b * SEQ * QKVD + h * HD;          // three=0
  const float* kbase = qbase + DIMD;                                    // three=1
  const float* vbase = qbase + 2 * DIMD;                                // three=2

  __shared__ float Qs[ATQ][HD + 1];
  __shared__ float Ks[ATK][HD + 1];
  __shared__ float Vs[ATK][HD + 1];
  __shared__ float Ps[ATQ][ATK + 4];   // pad 4: 2-way-free reads, 4-way writes

  const int t = threadIdx.x;
  const int g = t >> 4;   // 0..15
  const int c = t & 15;   // 0..15

  // load Q tile (64 x 48)
  for (int idx = t; idx < ATQ * HD; idx += 256) {
    int r = idx / HD, e = idx - r * HD;
    Qs[r][e] = qbase[(size_t)(qt * ATQ + r) * QKVD + e];
  }

  float m[4], l[4], o[4][3];
#pragma unroll
  for (int i = 0; i < 4; ++i) {
    m[i] = -1e30f;
    l[i] = 0.f;
    o[i][0] = o[i][1] = o[i][2] = 0.f;
  }

  for (int kt = 0; kt < SEQ / ATK; ++kt) {
    __syncthreads();   // previous tile's LDS readers done
    for (int idx = t; idx < ATK * HD; idx += 256) {
      int r = idx / HD, e = idx - r * HD;
      size_t goff = (size_t)(kt * ATK + r) * QKVD + e;
      Ks[r][e] = kbase[goff];
      Vs[r][e] = vbase[goff];
    }
    __syncthreads();   // K/V tile ready

    // ---- scores: s[i][j] = Q[4g+i] . K[4c+j] ----
    float s[4][4] = {{0.f, 0.f, 0.f, 0.f}, {0.f, 0.f, 0.f, 0.f},
                     {0.f, 0.f, 0.f, 0.f}, {0.f, 0.f, 0.f, 0.f}};
#pragma unroll 4
    for (int e = 0; e < HD; ++e) {
      float q[4], k[4];
#pragma unroll
      for (int i = 0; i < 4; ++i) q[i] = Qs[(g << 2) + i][e];
#pragma unroll
      for (int j = 0; j < 4; ++j) k[j] = Ks[(c << 2) + j][e];
#pragma unroll
      for (int i = 0; i < 4; ++i)
#pragma unroll
        for (int j = 0; j < 4; ++j)
          s[i][j] = fmaf(q[i], k[j], s[i][j]);
    }

    // ---- online softmax update (per row, reduced over the 16 c-lanes) ----
#pragma unroll
    for (int i = 0; i < 4; ++i) {
#pragma unroll
      for (int j = 0; j < 4; ++j) s[i][j] *= ATT_SCALE;
      float mx = fmaxf(fmaxf(s[i][0], s[i][1]), fmaxf(s[i][2], s[i][3]));
#pragma unroll
      for (int off = 8; off > 0; off >>= 1)
        mx = fmaxf(mx, __shfl_xor(mx, off, 16));
      float mn = fmaxf(m[i], mx);
      float corr = __expf(m[i] - mn);
      float rs = 0.f;
#pragma unroll
      for (int j = 0; j < 4; ++j) {
        s[i][j] = __expf(s[i][j] - mn);
        rs += s[i][j];
      }
#pragma unroll
      for (int off = 8; off > 0; off >>= 1)
        rs += __shfl_xor(rs, off, 16);
      l[i] = l[i] * corr + rs;
      m[i] = mn;
      o[i][0] *= corr;
      o[i][1] *= corr;
      o[i][2] *= corr;
#pragma unroll
      for (int j = 0; j < 4; ++j) Ps[(g << 2) + i][(c << 2) + j] = s[i][j];
    }
    __syncthreads();   // P tile ready

    // ---- PV accumulate: o[i][d] += sum_k P[row][k] * V[k][3c+d] ----
#pragma unroll 8
    for (int k = 0; k < ATK; ++k) {
      float p[4], vv[3];
#pragma unroll
      for (int i = 0; i < 4; ++i) p[i] = Ps[(g << 2) + i][k];
#pragma unroll
      for (int d = 0; d < 3; ++d) vv[d] = Vs[k][c * 3 + d];
#pragma unroll
      for (int i = 0; i < 4; ++i)
#pragma unroll
        for (int d = 0; d < 3; ++d)
          o[i][d] = fmaf(p[i], vv[d], o[i][d]);
    }
  }

  // ---- epilogue: divide by l, write A[b, s, h*48 + e] ----
#pragma unroll
  for (int i = 0; i < 4; ++i) {
    float inv = 1.0f / l[i];
    int srow = qt * ATQ + (g << 2) + i;
    float* dst = Aout + ((size_t)b * SEQ + srow) * DIMD + h * HD + c * 3;
    dst[0] = o[i][0] * inv;
    dst[1] = o[i][1] * inv;
    dst[2] = o[i][2] * inv;
  }
}

// ---------------------------------------------------------------------------
extern "C" void kernel_launch(void* const* d_in, const int* in_sizes, int n_in,
                              void* d_out, int out_size, void* d_ws, size_t ws_size,
                              hipStream_t stream) {
  const float* x      = (const float*)d_in[0];   // [4,2048,768]
  const float* w_qkv  = (const float*)d_in[1];   // [768,2304]
  const float* w_proj = (const float*)d_in[2];   // [768,768]
  const float* b_proj = (const float*)d_in[3];   // [768]
  float* out = (float*)d_out;                    // [4,2048,768]

  // workspace: qkv [8192,2304] fp32 (75.5 MB) + att [8192,768] fp32 (25.2 MB)
  float* qkv = (float*)d_ws;
  float* att = qkv + (size_t)NTOK * QKVD;

  // 1) qkv = x @ w_qkv
  gemm_f32<<<dim3(QKVD / BN, NTOK / BM), 256, 0, stream>>>(
      x, w_qkv, nullptr, qkv, NTOK, QKVD, DIMD);

  // 2) attention per (b,h,q-tile)
  attn_f32<<<dim3(SEQ / ATQ, BATCH * HEADS), 256, 0, stream>>>(qkv, att);

  // 3) out = att @ w_proj + b_proj
  gemm_f32<<<dim3(DIMD / BN, NTOK / BM), 256, 0, stream>>>(
      att, w_proj, b_proj, out, NTOK, DIMD, DIMD);
}

// Round 2
// 675.160 us; speedup vs baseline: 2.8894x; 2.8894x over previous
//
#include <hip/hip_runtime.h>
#include <hip/hip_bf16.h>

// Problem constants
#define DIMD   768
#define HEADS  16
#define HD     48
#define SEQ    2048
#define BATCH  4
#define NTOK   (BATCH * SEQ)     // 8192
#define QKVD   (3 * DIMD)        // 2304

typedef __attribute__((ext_vector_type(8)))  short s16x8;
typedef __attribute__((ext_vector_type(4)))  float f32x4;
typedef __attribute__((ext_vector_type(16))) float f32x16;

static __device__ __forceinline__ unsigned short f2b(float f) {
  union { __hip_bfloat16 b; unsigned short s; } u;
  u.b = __float2bfloat16(f);
  return u.s;
}

// ---------------------------------------------------------------------------
// fp32 tiled GEMM (unchanged from round 1): C = A@B (+bias)
// ---------------------------------------------------------------------------
#define BM 64
#define BN 64
#define BK 16

__global__ __launch_bounds__(256) void gemm_f32(
    const float* __restrict__ A, const float* __restrict__ B,
    const float* __restrict__ bias, float* __restrict__ C,
    int M, int N, int K) {
  __shared__ float As[BK][BM];
  __shared__ float Bs[BK][BN];

  const int t  = threadIdx.x;
  const int tx = t & 15;
  const int ty = t >> 4;
  const int m0 = blockIdx.y * BM;
  const int n0 = blockIdx.x * BN;

  const int arow = t >> 2;
  const int acol = (t & 3) << 2;
  const int brow = t >> 4;
  const int bcol = (t & 15) << 2;

  float acc[4][4] = {{0.f,0.f,0.f,0.f},{0.f,0.f,0.f,0.f},
                     {0.f,0.f,0.f,0.f},{0.f,0.f,0.f,0.f}};

  for (int k0 = 0; k0 < K; k0 += BK) {
    __syncthreads();
    float4 av = *(const float4*)(A + (size_t)(m0 + arow) * K + (k0 + acol));
    float4 bv = *(const float4*)(B + (size_t)(k0 + brow) * N + (n0 + bcol));
    As[acol + 0][arow] = av.x;
    As[acol + 1][arow] = av.y;
    As[acol + 2][arow] = av.z;
    As[acol + 3][arow] = av.w;
    *(float4*)&Bs[brow][bcol] = bv;
    __syncthreads();

#pragma unroll
    for (int kk = 0; kk < BK; ++kk) {
      float4 a = *(const float4*)&As[kk][ty << 2];
      float4 b = *(const float4*)&Bs[kk][tx << 2];
      float ar[4] = {a.x, a.y, a.z, a.w};
      float br[4] = {b.x, b.y, b.z, b.w};
#pragma unroll
      for (int i = 0; i < 4; ++i)
#pragma unroll
        for (int j = 0; j < 4; ++j)
          acc[i][j] = fmaf(ar[i], br[j], acc[i][j]);
    }
  }

  const int colg = n0 + (tx << 2);
  float4 bb = {0.f, 0.f, 0.f, 0.f};
  if (bias) bb = *(const float4*)(bias + colg);
#pragma unroll
  for (int i = 0; i < 4; ++i) {
    size_t row = (size_t)(m0 + (ty << 2) + i);
    float4 v;
    v.x = acc[i][0] + bb.x;
    v.y = acc[i][1] + bb.y;
    v.z = acc[i][2] + bb.z;
    v.w = acc[i][3] + bb.w;
    *(float4*)(C + row * N + colg) = v;
  }
}

// ---------------------------------------------------------------------------
// bf16-MFMA flash attention.
// Block = 4 waves; wave owns 32 q-rows; KV tiles of 64.
// Swapped QK^T: S^T[key][q] = mfma_32x32x16(K_tile, Q)  (K-dim = hd = 48 = 3 steps)
//   -> lane holds one q-row (lane&31); softmax lane-local + shfl_xor(32).
// Swapped PV:   O^T[hd][q]  = mfma_16x16x32(V^T, P^T)   (K-dim = keys, 2 steps)
// LDS: Kfrag (fragment-major, conflict-free b128), Vt/Ps XOR-swizzled.
// ---------------------------------------------------------------------------
#define KVB 64
#define QPW 32
#define QPB 128

__global__ __launch_bounds__(256) void attn_mfma(const float* __restrict__ QKV,
                                                 float* __restrict__ Aout) {
  const int bh = blockIdx.x;   // 0..63  (fast dim -> id%8 = bh%8: q-tiles of a bh share an XCD)
  const int qt = blockIdx.y;   // 0..15
  const int b = bh >> 4, h = bh & 15;
  const int tid  = threadIdx.x;
  const int w    = tid >> 6;
  const int lane = tid & 63;
  const int l31  = lane & 31;
  const int hi   = lane >> 5;
  const int l15  = lane & 15;
  const int l4   = lane >> 4;   // 0..3

  __shared__ __align__(16) short Kfrag[6 * 64 * 8];   // [kk*3+ks][lane][8]  6 KB
  __shared__ __align__(16) short Vt[48 * 64];         // swizzled [hd][key]  6 KB
  __shared__ __align__(16) short Ps[4][32 * 64];      // per-wave [q][key]  16 KB

  const float* qkv_b = QKV + (size_t)b * SEQ * QKVD;

  // --- Q fragments: lane&31 = q-row, (lane>>5)*8+j = hd within 16-chunk ---
  const float qs = 0.14433756729740643f * 1.44269504088896340f;  // scale * log2(e)
  const int qrow = qt * QPB + w * QPW + l31;
  const float* qsrc = qkv_b + (size_t)qrow * QKVD + h * HD;
  s16x8 qf[3];
#pragma unroll
  for (int ks = 0; ks < 3; ++ks) {
    const float* sp = qsrc + ks * 16 + hi * 8;
    float4 a = *(const float4*)sp;
    float4 c = *(const float4*)(sp + 4);
    s16x8 v;
    v[0] = (short)f2b(a.x * qs); v[1] = (short)f2b(a.y * qs);
    v[2] = (short)f2b(a.z * qs); v[3] = (short)f2b(a.w * qs);
    v[4] = (short)f2b(c.x * qs); v[5] = (short)f2b(c.y * qs);
    v[6] = (short)f2b(c.z * qs); v[7] = (short)f2b(c.w * qs);
    qf[ks] = v;
  }

  f32x4 o[3][2];
#pragma unroll
  for (int m = 0; m < 3; ++m)
#pragma unroll
    for (int n = 0; n < 2; ++n) {
      o[m][n][0] = 0.f; o[m][n][1] = 0.f; o[m][n][2] = 0.f; o[m][n][3] = 0.f;
    }
  float mreg = -3.0e38f, lreg = 0.f;

  // staging: thread -> (key sr, hd-block sp of 12)
  const int sr = tid & 63;
  const int spart = tid >> 6;
  const float* kbase = qkv_b + (size_t)sr * QKVD + DIMD + h * HD + spart * 12;
  const float* vbase = kbase + DIMD;
  short* ps = &Ps[w][0];

  for (int kt = 0; kt < SEQ / KVB; ++kt) {
    __syncthreads();
    const float* ksrc = kbase + (size_t)kt * KVB * QKVD;
    const float* vsrc = vbase + (size_t)kt * KVB * QKVD;
#pragma unroll
    for (int c = 0; c < 3; ++c) {
      const int e = spart * 12 + c * 4;
      float4 kv = *(const float4*)(ksrc + c * 4);
      const int kk = sr >> 5, kst = e >> 4, hh = (e >> 3) & 1, j = e & 7;
      uint2 pk;
      pk.x = (unsigned)f2b(kv.x) | ((unsigned)f2b(kv.y) << 16);
      pk.y = (unsigned)f2b(kv.z) | ((unsigned)f2b(kv.w) << 16);
      *(uint2*)&Kfrag[(((kk * 3 + kst) * 64 + (sr & 31) + 32 * hh) << 3) + j] = pk;

      float4 vv = *(const float4*)(vsrc + c * 4);
      Vt[(e + 0) * 64 + (sr ^ (((e + 0) & 7) << 3))] = (short)f2b(vv.x);
      Vt[(e + 1) * 64 + (sr ^ (((e + 1) & 7) << 3))] = (short)f2b(vv.y);
      Vt[(e + 2) * 64 + (sr ^ (((e + 2) & 7) << 3))] = (short)f2b(vv.z);
      Vt[(e + 3) * 64 + (sr ^ (((e + 3) & 7) << 3))] = (short)f2b(vv.w);
    }
    __syncthreads();

    // ---- QK^T swapped: two 32-key subtiles ----
    f32x16 s0, s1;
#pragma unroll
    for (int r = 0; r < 16; ++r) { s0[r] = 0.f; s1[r] = 0.f; }
#pragma unroll
    for (int ks = 0; ks < 3; ++ks) {
      s16x8 a0 = *(const s16x8*)&Kfrag[((0 * 3 + ks) * 64 + lane) << 3];
      s0 = __builtin_amdgcn_mfma_f32_32x32x16_bf16(a0, qf[ks], s0, 0, 0, 0);
      s16x8 a1 = *(const s16x8*)&Kfrag[((1 * 3 + ks) * 64 + lane) << 3];
      s1 = __builtin_amdgcn_mfma_f32_32x32x16_bf16(a1, qf[ks], s1, 0, 0, 0);
    }

    // ---- online softmax (log2 domain); lane owns q-row = lane&31 ----
    float mx = s0[0];
#pragma unroll
    for (int r = 1; r < 16; ++r) mx = fmaxf(mx, s0[r]);
#pragma unroll
    for (int r = 0; r < 16; ++r) mx = fmaxf(mx, s1[r]);
    mx = fmaxf(mx, __shfl_xor(mx, 32, 64));
    const float mn = fmaxf(mreg, mx);
    const float corr = __builtin_amdgcn_exp2f(mreg - mn);
    float rs = 0.f;
#pragma unroll
    for (int r = 0; r < 16; ++r) { s0[r] = __builtin_amdgcn_exp2f(s0[r] - mn); rs += s0[r]; }
#pragma unroll
    for (int r = 0; r < 16; ++r) { s1[r] = __builtin_amdgcn_exp2f(s1[r] - mn); rs += s1[r]; }
    rs += __shfl_xor(rs, 32, 64);
    lreg = lreg * corr + rs;
    mreg = mn;

    // ---- pack P -> Ps[q][key] (bf16, swizzled); regs 4g..4g+3 = keys 8g+4hi+0..3 ----
#pragma unroll
    for (int g = 0; g < 4; ++g) {
      int key0 = 8 * g + 4 * hi;
      uint2 pk;
      pk.x = (unsigned)f2b(s0[4 * g + 0]) | ((unsigned)f2b(s0[4 * g + 1]) << 16);
      pk.y = (unsigned)f2b(s0[4 * g + 2]) | ((unsigned)f2b(s0[4 * g + 3]) << 16);
      *(uint2*)&ps[l31 * 64 + ((key0) ^ ((l31 & 7) << 3))] = pk;
      pk.x = (unsigned)f2b(s1[4 * g + 0]) | ((unsigned)f2b(s1[4 * g + 1]) << 16);
      pk.y = (unsigned)f2b(s1[4 * g + 2]) | ((unsigned)f2b(s1[4 * g + 3]) << 16);
      *(uint2*)&ps[l31 * 64 + ((key0 + 32) ^ ((l31 & 7) << 3))] = pk;
    }

    // ---- rescale O by corr (per O-column q = l15 + 16n) ----
    const float c0 = __shfl(corr, l15, 64);
    const float c1 = __shfl(corr, l15 + 16, 64);
#pragma unroll
    for (int m = 0; m < 3; ++m)
#pragma unroll
      for (int i = 0; i < 4; ++i) { o[m][0][i] *= c0; o[m][1][i] *= c1; }

    // ---- PV swapped: O^T += V^T @ P^T ----
#pragma unroll
    for (int kv = 0; kv < 2; ++kv) {
      const int key0 = l4 * 8 + kv * 32;
      s16x8 pb0 = *(const s16x8*)&ps[l15 * 64 + (key0 ^ ((l15 & 7) << 3))];
      s16x8 pb1 = *(const s16x8*)&ps[(l15 + 16) * 64 + (key0 ^ ((l15 & 7) << 3))];
#pragma unroll
      for (int m = 0; m < 3; ++m) {
        const int hd0 = l15 + 16 * m;
        s16x8 va = *(const s16x8*)&Vt[hd0 * 64 + (key0 ^ ((hd0 & 7) << 3))];
        o[m][0] = __builtin_amdgcn_mfma_f32_16x16x32_bf16(va, pb0, o[m][0], 0, 0, 0);
        o[m][1] = __builtin_amdgcn_mfma_f32_16x16x32_bf16(va, pb1, o[m][1], 0, 0, 0);
      }
    }
  }

  // ---- epilogue: divide by l, store float4 (4 consecutive hd) ----
  const float li0 = __shfl(lreg, l15, 64);
  const float li1 = __shfl(lreg, l15 + 16, 64);
  const float i0 = 1.f / li0, i1 = 1.f / li1;
#pragma unroll
  for (int m = 0; m < 3; ++m)
#pragma unroll
    for (int n = 0; n < 2; ++n) {
      const float inv = n ? i1 : i0;
      const int srow = qt * QPB + w * QPW + n * 16 + l15;
      float* dst = Aout + ((size_t)b * SEQ + srow) * DIMD + h * HD + m * 16 + l4 * 4;
      float4 v;
      v.x = o[m][n][0] * inv;
      v.y = o[m][n][1] * inv;
      v.z = o[m][n][2] * inv;
      v.w = o[m][n][3] * inv;
      *(float4*)dst = v;
    }
}

// ---------------------------------------------------------------------------
extern "C" void kernel_launch(void* const* d_in, const int* in_sizes, int n_in,
                              void* d_out, int out_size, void* d_ws, size_t ws_size,
                              hipStream_t stream) {
  const float* x      = (const float*)d_in[0];
  const float* w_qkv  = (const float*)d_in[1];
  const float* w_proj = (const float*)d_in[2];
  const float* b_proj = (const float*)d_in[3];
  float* out = (float*)d_out;

  float* qkv = (float*)d_ws;                       // [8192,2304] fp32
  float* att = qkv + (size_t)NTOK * QKVD;          // [8192,768]  fp32

  gemm_f32<<<dim3(QKVD / BN, NTOK / BM), 256, 0, stream>>>(
      x, w_qkv, nullptr, qkv, NTOK, QKVD, DIMD);

  attn_mfma<<<dim3(BATCH * HEADS, SEQ / QPB), 256, 0, stream>>>(qkv, att);

  gemm_f32<<<dim3(DIMD / BN, NTOK / BM), 256, 0, stream>>>(
      att, w_proj, b_proj, out, NTOK, DIMD, DIMD);
}

// Round 3
// 220.764 us; speedup vs baseline: 8.8366x; 3.0583x over previous
//
#include <hip/hip_runtime.h>
#include <hip/hip_bf16.h>

// Problem constants
#define DIMD   768
#define HEADS  16
#define HD     48
#define SEQ    2048
#define BATCH  4
#define NTOK   (BATCH * SEQ)     // 8192
#define QKVD   (3 * DIMD)        // 2304

typedef __attribute__((ext_vector_type(8)))  short s16x8;
typedef __attribute__((ext_vector_type(4)))  float f32x4;
typedef __attribute__((ext_vector_type(16))) float f32x16;
typedef unsigned short ushort_t;

static __device__ __forceinline__ unsigned short f2b(float f) {
  union { __hip_bfloat16 b; unsigned short s; } u;
  u.b = __float2bfloat16(f);
  return u.s;
}
static __device__ __forceinline__ float b2f(unsigned short v) {
  union { float f; unsigned u; } x;
  x.u = ((unsigned)v) << 16;
  return x.f;
}

static __device__ __forceinline__ void gload_lds16(const void* g, void* l) {
  __builtin_amdgcn_global_load_lds(
      (const __attribute__((address_space(1))) unsigned int*)g,
      (__attribute__((address_space(3))) unsigned int*)l, 16, 0, 0);
}

// ---------------------------------------------------------------------------
// convert fp32 -> bf16 (row-major, 8 elems/thread)
// ---------------------------------------------------------------------------
__global__ __launch_bounds__(256) void cvt_bf16(const float* __restrict__ in,
                                                ushort_t* __restrict__ out, int n8) {
  int i = blockIdx.x * 256 + threadIdx.x;
  if (i >= n8) return;
  float4 a = ((const float4*)in)[i * 2];
  float4 b = ((const float4*)in)[i * 2 + 1];
  s16x8 v;
  v[0] = (short)f2b(a.x); v[1] = (short)f2b(a.y);
  v[2] = (short)f2b(a.z); v[3] = (short)f2b(a.w);
  v[4] = (short)f2b(b.x); v[5] = (short)f2b(b.y);
  v[6] = (short)f2b(b.z); v[7] = (short)f2b(b.w);
  ((s16x8*)out)[i] = v;
}

// ---------------------------------------------------------------------------
// transpose + convert: out[c][r] = bf16(in[r][c]); 32x32 LDS tiles
// ---------------------------------------------------------------------------
__global__ __launch_bounds__(256) void tcvt_bf16(const float* __restrict__ in,
                                                 ushort_t* __restrict__ out,
                                                 int R, int C) {
  __shared__ float T[32][33];
  const int c0 = blockIdx.x * 32, r0 = blockIdx.y * 32;
  const int lc = threadIdx.x & 31, lr = threadIdx.x >> 5;   // 8 rows/pass
#pragma unroll
  for (int i = 0; i < 4; ++i)
    T[lr + 8 * i][lc] = in[(size_t)(r0 + lr + 8 * i) * C + c0 + lc];
  __syncthreads();
#pragma unroll
  for (int i = 0; i < 4; ++i)
    out[(size_t)(c0 + lr + 8 * i) * R + r0 + lc] = f2b(T[lc][lr + 8 * i]);
}

// ---------------------------------------------------------------------------
// bf16 MFMA GEMM (m97 structure): C[M,N] = A[M,K] @ Bt[N,K]^T
// 128x128 tile, BK=64, 4 waves (2x2 of 64x64), global_load_lds(16B),
// G4 swizzle: LDS[row][c16] holds Global[row][c16 ^ (row&7)].
// OUT_BF16=1 -> bf16 C; else fp32 C + bias.
// ---------------------------------------------------------------------------
template <int OUT_BF16>
__global__ __launch_bounds__(256) void gemm_bf16(
    const ushort_t* __restrict__ A, const ushort_t* __restrict__ Bt,
    const float* __restrict__ bias, void* __restrict__ Cout,
    int M, int N, int K) {
  __shared__ __align__(16) ushort_t As[128 * 64];
  __shared__ __align__(16) ushort_t Bs[128 * 64];

  const int tid = threadIdx.x;
  const int lane = tid & 63;
  const int w = tid >> 6;
  const int m0 = blockIdx.y * 128, n0 = blockIdx.x * 128;
  const int wm = (w >> 1) * 64, wn = (w & 1) * 64;

  // staging: granule gidx = r*256+tid; row = gidx>>3, c16 = tid&7 (pre-swizzled src)
  const int c16s = (tid & 7) ^ ((tid >> 3) & 7);
  const ushort_t* aSrc = A + (size_t)(m0 + (tid >> 3)) * K + c16s * 8;
  const ushort_t* bSrc = Bt + (size_t)(n0 + (tid >> 3)) * K + c16s * 8;

  f32x4 acc[4][4];
#pragma unroll
  for (int i = 0; i < 4; ++i)
#pragma unroll
    for (int j = 0; j < 4; ++j) {
      acc[i][j][0] = 0.f; acc[i][j][1] = 0.f;
      acc[i][j][2] = 0.f; acc[i][j][3] = 0.f;
    }

  for (int k0 = 0; k0 < K; k0 += 64) {
    __syncthreads();   // prev readers done
#pragma unroll
    for (int r = 0; r < 4; ++r) {
      gload_lds16(aSrc + (size_t)(r * 32) * K + k0,
                  (char*)As + (r * 256 + w * 64) * 16);
      gload_lds16(bSrc + (size_t)(r * 32) * K + k0,
                  (char*)Bs + (r * 256 + w * 64) * 16);
    }
    __syncthreads();   // vmcnt(0) drained by compiler before barrier

#pragma unroll
    for (int ks = 0; ks < 2; ++ks) {
      s16x8 af[4], bfr[4];
#pragma unroll
      for (int i = 0; i < 4; ++i) {
        const int ar = wm + i * 16 + (lane & 15);
        const int ac = (ks * 4 + (lane >> 4)) ^ (ar & 7);
        af[i] = *(const s16x8*)&As[ar * 64 + ac * 8];
        const int br = wn + i * 16 + (lane & 15);
        const int bc = (ks * 4 + (lane >> 4)) ^ (br & 7);
        bfr[i] = *(const s16x8*)&Bs[br * 64 + bc * 8];
      }
#pragma unroll
      for (int i = 0; i < 4; ++i)
#pragma unroll
        for (int j = 0; j < 4; ++j)
          acc[i][j] = __builtin_amdgcn_mfma_f32_16x16x32_bf16(
              af[i], bfr[j], acc[i][j], 0, 0, 0);
    }
  }

  // epilogue: C/D layout col=lane&15, row=(lane>>4)*4+reg
  if (OUT_BF16) {
    ushort_t* C = (ushort_t*)Cout;
#pragma unroll
    for (int i = 0; i < 4; ++i)
#pragma unroll
      for (int j = 0; j < 4; ++j) {
        const int col = n0 + wn + j * 16 + (lane & 15);
#pragma unroll
        for (int r = 0; r < 4; ++r) {
          const int row = m0 + wm + i * 16 + (lane >> 4) * 4 + r;
          C[(size_t)row * N + col] = f2b(acc[i][j][r]);
        }
      }
  } else {
    float* C = (float*)Cout;
#pragma unroll
    for (int i = 0; i < 4; ++i)
#pragma unroll
      for (int j = 0; j < 4; ++j) {
        const int col = n0 + wn + j * 16 + (lane & 15);
        const float bv = bias ? bias[col] : 0.f;
#pragma unroll
        for (int r = 0; r < 4; ++r) {
          const int row = m0 + wm + i * 16 + (lane >> 4) * 4 + r;
          C[(size_t)row * N + col] = acc[i][j][r] + bv;
        }
      }
  }
}

// ---------------------------------------------------------------------------
// bf16-MFMA flash attention (round-2 structure, bf16 qkv in / bf16 att out).
// ---------------------------------------------------------------------------
#define KVB 64
#define QPW 32
#define QPB 128

__global__ __launch_bounds__(256) void attn_mfma(const ushort_t* __restrict__ QKV,
                                                 ushort_t* __restrict__ Aout) {
  const int bh = blockIdx.x;
  const int qt = blockIdx.y;
  const int b = bh >> 4, h = bh & 15;
  const int tid  = threadIdx.x;
  const int w    = tid >> 6;
  const int lane = tid & 63;
  const int l31  = lane & 31;
  const int hi   = lane >> 5;
  const int l15  = lane & 15;
  const int l4   = lane >> 4;

  __shared__ __align__(16) ushort_t Kfrag[6 * 64 * 8];  // [slot][pos^slot][8]
  __shared__ __align__(16) ushort_t Vt[48 * 64];        // swizzled [hd][key]
  __shared__ __align__(16) ushort_t Ps[4][32 * 64];     // per-wave [q][key]

  const ushort_t* qkv_b = QKV + (size_t)b * SEQ * QKVD;

  // --- Q fragments, pre-scaled by SCALE*log2(e) ---
  const float qs = 0.14433756729740643f * 1.44269504088896340f;
  const int qrow = qt * QPB + w * QPW + l31;
  const ushort_t* qsrc = qkv_b + (size_t)qrow * QKVD + h * HD;
  s16x8 qf[3];
#pragma unroll
  for (int ks = 0; ks < 3; ++ks) {
    s16x8 raw = *(const s16x8*)(qsrc + ks * 16 + hi * 8);
    s16x8 v;
#pragma unroll
    for (int j = 0; j < 8; ++j) v[j] = (short)f2b(b2f((unsigned short)raw[j]) * qs);
    qf[ks] = v;
  }

  f32x4 o[3][2];
#pragma unroll
  for (int m = 0; m < 3; ++m)
#pragma unroll
    for (int n = 0; n < 2; ++n) {
      o[m][n][0] = 0.f; o[m][n][1] = 0.f; o[m][n][2] = 0.f; o[m][n][3] = 0.f;
    }
  float mreg = -3.0e38f, lreg = 0.f;

  // staging: lane = key row, wave = granule (bank-friendly)
  const int srow = lane;
  const int g0 = w;
  ushort_t* ps = &Ps[w][0];

  for (int kt = 0; kt < SEQ / KVB; ++kt) {
    __syncthreads();
    const ushort_t* ksrc = qkv_b + (size_t)(kt * KVB) * QKVD + DIMD + h * HD;
    const ushort_t* vsrc = ksrc + DIMD;
    auto stage = [&](int g) {
      s16x8 k8 = *(const s16x8*)(ksrc + (size_t)srow * QKVD + g * 8);
      const int slot = (srow >> 5) * 3 + (g >> 1);
      const int pos = (((srow & 31) + ((g & 1) << 5)) ^ slot);
      *(s16x8*)&Kfrag[(slot * 64 + pos) * 8] = k8;
      s16x8 v8 = *(const s16x8*)(vsrc + (size_t)srow * QKVD + g * 8);
#pragma unroll
      for (int j = 0; j < 8; ++j)
        Vt[(8 * g + j) * 64 + (srow ^ (j << 3))] = (ushort_t)v8[j];
    };
    stage(g0);
    if (g0 < 2) stage(g0 + 4);
    __syncthreads();

    // ---- QK^T swapped: S^T[key][q] ----
    f32x16 s0, s1;
#pragma unroll
    for (int r = 0; r < 16; ++r) { s0[r] = 0.f; s1[r] = 0.f; }
#pragma unroll
    for (int ks = 0; ks < 3; ++ks) {
      s16x8 a0 = *(const s16x8*)&Kfrag[(ks * 64 + (lane ^ ks)) * 8];
      s0 = __builtin_amdgcn_mfma_f32_32x32x16_bf16(a0, qf[ks], s0, 0, 0, 0);
      s16x8 a1 = *(const s16x8*)&Kfrag[((3 + ks) * 64 + (lane ^ (3 + ks))) * 8];
      s1 = __builtin_amdgcn_mfma_f32_32x32x16_bf16(a1, qf[ks], s1, 0, 0, 0);
    }

    // ---- online softmax (exp2 domain); lane owns q-row = lane&31 ----
    float mx = s0[0];
#pragma unroll
    for (int r = 1; r < 16; ++r) mx = fmaxf(mx, s0[r]);
#pragma unroll
    for (int r = 0; r < 16; ++r) mx = fmaxf(mx, s1[r]);
    mx = fmaxf(mx, __shfl_xor(mx, 32, 64));
    const float mn = fmaxf(mreg, mx);
    const float corr = __builtin_amdgcn_exp2f(mreg - mn);
    float rs = 0.f;
#pragma unroll
    for (int r = 0; r < 16; ++r) { s0[r] = __builtin_amdgcn_exp2f(s0[r] - mn); rs += s0[r]; }
#pragma unroll
    for (int r = 0; r < 16; ++r) { s1[r] = __builtin_amdgcn_exp2f(s1[r] - mn); rs += s1[r]; }
    rs += __shfl_xor(rs, 32, 64);
    lreg = lreg * corr + rs;
    mreg = mn;

    // ---- pack P -> Ps[q][key] (bf16, swizzled) ----
#pragma unroll
    for (int g = 0; g < 4; ++g) {
      int key0 = 8 * g + 4 * hi;
      uint2 pk;
      pk.x = (unsigned)f2b(s0[4 * g + 0]) | ((unsigned)f2b(s0[4 * g + 1]) << 16);
      pk.y = (unsigned)f2b(s0[4 * g + 2]) | ((unsigned)f2b(s0[4 * g + 3]) << 16);
      *(uint2*)&ps[l31 * 64 + ((key0) ^ ((l31 & 7) << 3))] = pk;
      pk.x = (unsigned)f2b(s1[4 * g + 0]) | ((unsigned)f2b(s1[4 * g + 1]) << 16);
      pk.y = (unsigned)f2b(s1[4 * g + 2]) | ((unsigned)f2b(s1[4 * g + 3]) << 16);
      *(uint2*)&ps[l31 * 64 + ((key0 + 32) ^ ((l31 & 7) << 3))] = pk;
    }

    // ---- rescale O by corr ----
    const float c0 = __shfl(corr, l15, 64);
    const float c1 = __shfl(corr, l15 + 16, 64);
#pragma unroll
    for (int m = 0; m < 3; ++m)
#pragma unroll
      for (int i = 0; i < 4; ++i) { o[m][0][i] *= c0; o[m][1][i] *= c1; }

    // ---- PV swapped: O^T += V^T @ P^T ----
#pragma unroll
    for (int kv = 0; kv < 2; ++kv) {
      const int key0 = l4 * 8 + kv * 32;
      s16x8 pb0 = *(const s16x8*)&ps[l15 * 64 + (key0 ^ ((l15 & 7) << 3))];
      s16x8 pb1 = *(const s16x8*)&ps[(l15 + 16) * 64 + (key0 ^ ((l15 & 7) << 3))];
#pragma unroll
      for (int m = 0; m < 3; ++m) {
        const int hd0 = l15 + 16 * m;
        s16x8 va = *(const s16x8*)&Vt[hd0 * 64 + (key0 ^ ((hd0 & 7) << 3))];
        o[m][0] = __builtin_amdgcn_mfma_f32_16x16x32_bf16(va, pb0, o[m][0], 0, 0, 0);
        o[m][1] = __builtin_amdgcn_mfma_f32_16x16x32_bf16(va, pb1, o[m][1], 0, 0, 0);
      }
    }
  }

  // ---- epilogue: bf16 att output ----
  const float li0 = __shfl(lreg, l15, 64);
  const float li1 = __shfl(lreg, l15 + 16, 64);
  const float i0 = 1.f / li0, i1 = 1.f / li1;
#pragma unroll
  for (int m = 0; m < 3; ++m)
#pragma unroll
    for (int n = 0; n < 2; ++n) {
      const float inv = n ? i1 : i0;
      const int srow_ = qt * QPB + w * QPW + n * 16 + l15;
      ushort_t* dst = Aout + ((size_t)b * SEQ + srow_) * DIMD + h * HD + m * 16 + l4 * 4;
      uint2 pk;
      pk.x = (unsigned)f2b(o[m][n][0] * inv) | ((unsigned)f2b(o[m][n][1] * inv) << 16);
      pk.y = (unsigned)f2b(o[m][n][2] * inv) | ((unsigned)f2b(o[m][n][3] * inv) << 16);
      *(uint2*)dst = pk;
    }
}

// ---------------------------------------------------------------------------
extern "C" void kernel_launch(void* const* d_in, const int* in_sizes, int n_in,
                              void* d_out, int out_size, void* d_ws, size_t ws_size,
                              hipStream_t stream) {
  const float* x      = (const float*)d_in[0];   // [8192,768]
  const float* w_qkv  = (const float*)d_in[1];   // [768,2304]
  const float* w_proj = (const float*)d_in[2];   // [768,768]
  const float* b_proj = (const float*)d_in[3];   // [768]
  float* out = (float*)d_out;

  ushort_t* xb     = (ushort_t*)d_ws;                  // [8192,768]  bf16
  ushort_t* wqkvT  = xb + (size_t)NTOK * DIMD;         // [2304,768]  bf16 (transposed)
  ushort_t* wprojT = wqkvT + (size_t)QKVD * DIMD;      // [768,768]   bf16 (transposed)
  ushort_t* qkv    = wprojT + (size_t)DIMD * DIMD;     // [8192,2304] bf16
  ushort_t* att    = qkv + (size_t)NTOK * QKVD;        // [8192,768]  bf16

  // converts
  cvt_bf16<<<(NTOK * DIMD / 8 + 255) / 256, 256, 0, stream>>>(x, xb, NTOK * DIMD / 8);
  tcvt_bf16<<<dim3(QKVD / 32, DIMD / 32), 256, 0, stream>>>(w_qkv, wqkvT, DIMD, QKVD);
  tcvt_bf16<<<dim3(DIMD / 32, DIMD / 32), 256, 0, stream>>>(w_proj, wprojT, DIMD, DIMD);

  // qkv = x @ w_qkv   (bf16 out)
  gemm_bf16<1><<<dim3(QKVD / 128, NTOK / 128), 256, 0, stream>>>(
      xb, wqkvT, nullptr, qkv, NTOK, QKVD, DIMD);

  // attention
  attn_mfma<<<dim3(BATCH * HEADS, SEQ / QPB), 256, 0, stream>>>(qkv, att);

  // out = att @ w_proj + b_proj   (fp32 out)
  gemm_bf16<0><<<dim3(DIMD / 128, NTOK / 128), 256, 0, stream>>>(
      att, wprojT, b_proj, out, NTOK, DIMD, DIMD);
}

// Round 4
// 187.811 us; speedup vs baseline: 10.3871x; 1.1755x over previous
//
#include <hip/hip_runtime.h>
#include <hip/hip_bf16.h>

// Problem constants
#define DIMD   768
#define HEADS  16
#define HD     48
#define SEQ    2048
#define BATCH  4
#define NTOK   (BATCH * SEQ)     // 8192
#define QKVD   (3 * DIMD)        // 2304

typedef __attribute__((ext_vector_type(8)))  short s16x8;
typedef __attribute__((ext_vector_type(4)))  float f32x4;
typedef __attribute__((ext_vector_type(16))) float f32x16;
typedef unsigned short ushort_t;

static __device__ __forceinline__ unsigned short f2b(float f) {
  union { __hip_bfloat16 b; unsigned short s; } u;
  u.b = __float2bfloat16(f);
  return u.s;
}
static __device__ __forceinline__ float b2f(unsigned short v) {
  union { float f; unsigned u; } x;
  x.u = ((unsigned)v) << 16;
  return x.f;
}
static __device__ __forceinline__ unsigned pk2(float a, float b) {
  return (unsigned)f2b(a) | ((unsigned)f2b(b) << 16);
}

static __device__ __forceinline__ void gload_lds16(const void* g, void* l) {
  __builtin_amdgcn_global_load_lds(
      (const __attribute__((address_space(1))) unsigned int*)g,
      (__attribute__((address_space(3))) unsigned int*)l, 16, 0, 0);
}

// ---------------------------------------------------------------------------
// convert fp32 -> bf16 (row-major, 8 elems/thread)
// ---------------------------------------------------------------------------
__global__ __launch_bounds__(256) void cvt_bf16(const float* __restrict__ in,
                                                ushort_t* __restrict__ out, int n8) {
  int i = blockIdx.x * 256 + threadIdx.x;
  if (i >= n8) return;
  float4 a = ((const float4*)in)[i * 2];
  float4 b = ((const float4*)in)[i * 2 + 1];
  s16x8 v;
  v[0] = (short)f2b(a.x); v[1] = (short)f2b(a.y);
  v[2] = (short)f2b(a.z); v[3] = (short)f2b(a.w);
  v[4] = (short)f2b(b.x); v[5] = (short)f2b(b.y);
  v[6] = (short)f2b(b.z); v[7] = (short)f2b(b.w);
  ((s16x8*)out)[i] = v;
}

// ---------------------------------------------------------------------------
// transpose + convert: out[c][r] = bf16(in[r][c]); 32x32 LDS tiles
// ---------------------------------------------------------------------------
__global__ __launch_bounds__(256) void tcvt_bf16(const float* __restrict__ in,
                                                 ushort_t* __restrict__ out,
                                                 int R, int C) {
  __shared__ float T[32][33];
  const int c0 = blockIdx.x * 32, r0 = blockIdx.y * 32;
  const int lc = threadIdx.x & 31, lr = threadIdx.x >> 5;
#pragma unroll
  for (int i = 0; i < 4; ++i)
    T[lr + 8 * i][lc] = in[(size_t)(r0 + lr + 8 * i) * C + c0 + lc];
  __syncthreads();
#pragma unroll
  for (int i = 0; i < 4; ++i)
    out[(size_t)(c0 + lr + 8 * i) * R + r0 + lc] = f2b(T[lc][lr + 8 * i]);
}

// ---------------------------------------------------------------------------
// bf16 MFMA GEMM (m97 structure, unchanged from round 3)
// ---------------------------------------------------------------------------
template <int OUT_BF16>
__global__ __launch_bounds__(256) void gemm_bf16(
    const ushort_t* __restrict__ A, const ushort_t* __restrict__ Bt,
    const float* __restrict__ bias, void* __restrict__ Cout,
    int M, int N, int K) {
  __shared__ __align__(16) ushort_t As[128 * 64];
  __shared__ __align__(16) ushort_t Bs[128 * 64];

  const int tid = threadIdx.x;
  const int lane = tid & 63;
  const int w = tid >> 6;
  const int m0 = blockIdx.y * 128, n0 = blockIdx.x * 128;
  const int wm = (w >> 1) * 64, wn = (w & 1) * 64;

  const int c16s = (tid & 7) ^ ((tid >> 3) & 7);
  const ushort_t* aSrc = A + (size_t)(m0 + (tid >> 3)) * K + c16s * 8;
  const ushort_t* bSrc = Bt + (size_t)(n0 + (tid >> 3)) * K + c16s * 8;

  f32x4 acc[4][4];
#pragma unroll
  for (int i = 0; i < 4; ++i)
#pragma unroll
    for (int j = 0; j < 4; ++j) {
      acc[i][j][0] = 0.f; acc[i][j][1] = 0.f;
      acc[i][j][2] = 0.f; acc[i][j][3] = 0.f;
    }

  for (int k0 = 0; k0 < K; k0 += 64) {
    __syncthreads();
#pragma unroll
    for (int r = 0; r < 4; ++r) {
      gload_lds16(aSrc + (size_t)(r * 32) * K + k0,
                  (char*)As + (r * 256 + w * 64) * 16);
      gload_lds16(bSrc + (size_t)(r * 32) * K + k0,
                  (char*)Bs + (r * 256 + w * 64) * 16);
    }
    __syncthreads();

#pragma unroll
    for (int ks = 0; ks < 2; ++ks) {
      s16x8 af[4], bfr[4];
#pragma unroll
      for (int i = 0; i < 4; ++i) {
        const int ar = wm + i * 16 + (lane & 15);
        const int ac = (ks * 4 + (lane >> 4)) ^ (ar & 7);
        af[i] = *(const s16x8*)&As[ar * 64 + ac * 8];
        const int br = wn + i * 16 + (lane & 15);
        const int bc = (ks * 4 + (lane >> 4)) ^ (br & 7);
        bfr[i] = *(const s16x8*)&Bs[br * 64 + bc * 8];
      }
#pragma unroll
      for (int i = 0; i < 4; ++i)
#pragma unroll
        for (int j = 0; j < 4; ++j)
          acc[i][j] = __builtin_amdgcn_mfma_f32_16x16x32_bf16(
              af[i], bfr[j], acc[i][j], 0, 0, 0);
    }
  }

  if (OUT_BF16) {
    ushort_t* C = (ushort_t*)Cout;
#pragma unroll
    for (int i = 0; i < 4; ++i)
#pragma unroll
      for (int j = 0; j < 4; ++j) {
        const int col = n0 + wn + j * 16 + (lane & 15);
#pragma unroll
        for (int r = 0; r < 4; ++r) {
          const int row = m0 + wm + i * 16 + (lane >> 4) * 4 + r;
          C[(size_t)row * N + col] = f2b(acc[i][j][r]);
        }
      }
  } else {
    float* C = (float*)Cout;
#pragma unroll
    for (int i = 0; i < 4; ++i)
#pragma unroll
      for (int j = 0; j < 4; ++j) {
        const int col = n0 + wn + j * 16 + (lane & 15);
        const float bv = bias ? bias[col] : 0.f;
#pragma unroll
        for (int r = 0; r < 4; ++r) {
          const int row = m0 + wm + i * 16 + (lane >> 4) * 4 + r;
          C[(size_t)row * N + col] = acc[i][j][r] + bv;
        }
      }
  }
}

// ---------------------------------------------------------------------------
// bf16-MFMA flash attention, round 4:
//  - QK^T swapped (32x32x16): lane owns q = lane&31, keys per reg.
//  - P stays in registers: cvt_pk pairs + v_permlane32_swap builds PV B-frags.
//  - PV: O^T[hd][q] = mfma_32x32x16(A = V^T from LDS, B = P^T in-reg).
//    O^T cols = q = lane&31 -> softmax state, rescale, 1/l all lane-local.
//  - T14 async stage split: next tile's K/V global->reg loads issue before
//    compute, LDS writes happen after the next barrier.
//  - T13 defer-max (THR=8), T5 setprio around MFMA clusters.
// ---------------------------------------------------------------------------
#define KVB 64
#define QPW 32
#define QPB 128

__global__ __launch_bounds__(256) void attn_mfma(const ushort_t* __restrict__ QKV,
                                                 ushort_t* __restrict__ Aout) {
  const int bh = blockIdx.x;   // fast dim: q-tiles of one (b,h) share an XCD
  const int qt = blockIdx.y;
  const int b = bh >> 4, h = bh & 15;
  const int tid  = threadIdx.x;
  const int w    = tid >> 6;
  const int lane = tid & 63;
  const int l31  = lane & 31;
  const int hi   = lane >> 5;

  __shared__ __align__(16) ushort_t Kfrag[6 * 64 * 8];  // 6 KB
  __shared__ __align__(16) ushort_t Vt[64 * 64];        // 8 KB [hd(pad 64)][key]

  // zero Vt pad rows 48..63 (read by m-tile1, never written by staging)
  *(uint2*)&Vt[48 * 64 + tid * 4] = make_uint2(0u, 0u);

  const ushort_t* qkv_b = QKV + (size_t)b * SEQ * QKVD;

  // --- Q fragments, pre-scaled by SCALE*log2(e) ---
  const float qs = 0.14433756729740643f * 1.44269504088896340f;
  const int qrow = qt * QPB + w * QPW + l31;
  const ushort_t* qsrc = qkv_b + (size_t)qrow * QKVD + h * HD;
  s16x8 qf[3];
#pragma unroll
  for (int ks = 0; ks < 3; ++ks) {
    s16x8 raw = *(const s16x8*)(qsrc + ks * 16 + hi * 8);
    s16x8 v;
#pragma unroll
    for (int j = 0; j < 8; ++j) v[j] = (short)f2b(b2f((unsigned short)raw[j]) * qs);
    qf[ks] = v;
  }

  f32x16 o[2];
#pragma unroll
  for (int mt = 0; mt < 2; ++mt)
#pragma unroll
    for (int r = 0; r < 16; ++r) o[mt][r] = 0.f;
  float mreg = -3.0e38f, lreg = 0.f;

  // staging assignment: lane = key row, wave w = hd-granule (wave 0/1 also 4/5)
  const int srow = lane;
  const int g0 = w;
  const ushort_t* kv0 = qkv_b + (size_t)srow * QKVD + DIMD + h * HD;

  s16x8 ka, va, kb, vb;
  auto loadKV = [&](int kt) {
    const ushort_t* base = kv0 + (size_t)(kt * KVB) * QKVD;
    ka = *(const s16x8*)(base + g0 * 8);
    va = *(const s16x8*)(base + DIMD + g0 * 8);
    if (g0 < 2) {
      kb = *(const s16x8*)(base + (g0 + 4) * 8);
      vb = *(const s16x8*)(base + DIMD + (g0 + 4) * 8);
    }
  };
  auto writeKV = [&]() {
    auto put = [&](int g, s16x8 k8, s16x8 v8) {
      const int slot = (srow >> 5) * 3 + (g >> 1);
      const int pos = (((srow & 31) + ((g & 1) << 5)) ^ slot);
      *(s16x8*)&Kfrag[(slot * 64 + pos) * 8] = k8;
#pragma unroll
      for (int j = 0; j < 8; ++j)
        Vt[(8 * g + j) * 64 + (srow ^ (j << 3))] = (ushort_t)v8[j];
    };
    put(g0, ka, va);
    if (g0 < 2) put(g0 + 4, kb, vb);
  };

  loadKV(0);

  for (int kt = 0; kt < SEQ / KVB; ++kt) {
    __syncthreads();   // LDS readers of previous tile done
    writeKV();
    __syncthreads();   // K/V tile ready
    if (kt + 1 < SEQ / KVB) loadKV(kt + 1);   // T14: overlap with compute

    // ---- QK^T swapped: S^T[key][q], two 32-key halves ----
    f32x16 s0, s1;
#pragma unroll
    for (int r = 0; r < 16; ++r) { s0[r] = 0.f; s1[r] = 0.f; }
    __builtin_amdgcn_s_setprio(1);
#pragma unroll
    for (int ks = 0; ks < 3; ++ks) {
      s16x8 a0 = *(const s16x8*)&Kfrag[(ks * 64 + (lane ^ ks)) * 8];
      s0 = __builtin_amdgcn_mfma_f32_32x32x16_bf16(a0, qf[ks], s0, 0, 0, 0);
      s16x8 a1 = *(const s16x8*)&Kfrag[((3 + ks) * 64 + (lane ^ (3 + ks))) * 8];
      s1 = __builtin_amdgcn_mfma_f32_32x32x16_bf16(a1, qf[ks], s1, 0, 0, 0);
    }
    __builtin_amdgcn_s_setprio(0);

    // ---- online softmax, lane-local (q = lane&31), exp2 domain ----
    float t[8];
#pragma unroll
    for (int i = 0; i < 8; ++i)
      t[i] = fmaxf(fmaxf(s0[i], s0[i + 8]), fmaxf(s1[i], s1[i + 8]));
#pragma unroll
    for (int i = 0; i < 4; ++i) t[i] = fmaxf(t[i], t[i + 4]);
    float mx = fmaxf(fmaxf(t[0], t[1]), fmaxf(t[2], t[3]));
    mx = fmaxf(mx, __shfl_xor(mx, 32, 64));

    if (!__all(mx <= mreg + 8.f)) {   // T13 defer-max
      const float mn = fmaxf(mreg, mx);
      const float corr = __builtin_amdgcn_exp2f(mreg - mn);
      mreg = mn;
      lreg *= corr;
#pragma unroll
      for (int mt = 0; mt < 2; ++mt)
#pragma unroll
        for (int r = 0; r < 16; ++r) o[mt][r] *= corr;
    }
    float rs = 0.f;
#pragma unroll
    for (int r = 0; r < 16; ++r) {
      s0[r] = __builtin_amdgcn_exp2f(s0[r] - mreg); rs += s0[r];
      s1[r] = __builtin_amdgcn_exp2f(s1[r] - mreg); rs += s1[r];
    }
    rs += __shfl_xor(rs, 32, 64);
    lreg += rs;

    // ---- pack P to bf16 pairs (keys (2g,2g+1) per word) ----
    unsigned pw0[8], pw1[8];
#pragma unroll
    for (int g = 0; g < 8; ++g) {
      pw0[g] = pk2(s0[2 * g], s0[2 * g + 1]);
      pw1[g] = pk2(s1[2 * g], s1[2 * g + 1]);
    }

    // ---- PV: O^T += V^T @ P^T ; P^T B-frags via permlane32_swap ----
    __builtin_amdgcn_s_setprio(1);
#pragma unroll
    for (int ks = 0; ks < 4; ++ks) {
      unsigned w0 = (ks < 2) ? pw0[4 * (ks & 1) + 0] : pw1[4 * (ks & 1) + 0];
      unsigned w1 = (ks < 2) ? pw0[4 * (ks & 1) + 1] : pw1[4 * (ks & 1) + 1];
      unsigned w2 = (ks < 2) ? pw0[4 * (ks & 1) + 2] : pw1[4 * (ks & 1) + 2];
      unsigned w3 = (ks < 2) ? pw0[4 * (ks & 1) + 3] : pw1[4 * (ks & 1) + 3];
      asm("v_permlane32_swap_b32 %0, %1" : "+v"(w0), "+v"(w2));
      asm("v_permlane32_swap_b32 %0, %1" : "+v"(w1), "+v"(w3));
      union { unsigned u[4]; s16x8 v; } pf;
      pf.u[0] = w0; pf.u[1] = w1; pf.u[2] = w2; pf.u[3] = w3;
      const int keyb = ks * 16 + hi * 8;
#pragma unroll
      for (int mt = 0; mt < 2; ++mt) {
        const int hd = mt * 32 + l31;
        s16x8 vfrag = *(const s16x8*)&Vt[hd * 64 + (keyb ^ ((hd & 7) << 3))];
        o[mt] = __builtin_amdgcn_mfma_f32_32x32x16_bf16(vfrag, pf.v, o[mt], 0, 0, 0);
      }
    }
    __builtin_amdgcn_s_setprio(0);
  }

  // ---- epilogue: lane-local 1/l, O^T rows -> bf16 pair stores ----
  const float inv = 1.f / lreg;
  const int token = qt * QPB + w * QPW + l31;
  ushort_t* dst = Aout + ((size_t)b * SEQ + token) * DIMD + h * HD;
#pragma unroll
  for (int rq = 0; rq < 4; ++rq) {      // m-tile0: hd = 8*rq + 4*hi + {0..3}
    const int hd0 = 8 * rq + 4 * hi;
    uint2 pk;
    pk.x = pk2(o[0][4 * rq + 0] * inv, o[0][4 * rq + 1] * inv);
    pk.y = pk2(o[0][4 * rq + 2] * inv, o[0][4 * rq + 3] * inv);
    *(uint2*)(dst + hd0) = pk;
  }
#pragma unroll
  for (int rq = 0; rq < 2; ++rq) {      // m-tile1: hd = 32 + 8*rq + 4*hi + {0..3}
    const int hd0 = 32 + 8 * rq + 4 * hi;
    uint2 pk;
    pk.x = pk2(o[1][4 * rq + 0] * inv, o[1][4 * rq + 1] * inv);
    pk.y = pk2(o[1][4 * rq + 2] * inv, o[1][4 * rq + 3] * inv);
    *(uint2*)(dst + hd0) = pk;
  }
}

// ---------------------------------------------------------------------------
extern "C" void kernel_launch(void* const* d_in, const int* in_sizes, int n_in,
                              void* d_out, int out_size, void* d_ws, size_t ws_size,
                              hipStream_t stream) {
  const float* x      = (const float*)d_in[0];
  const float* w_qkv  = (const float*)d_in[1];
  const float* w_proj = (const float*)d_in[2];
  const float* b_proj = (const float*)d_in[3];
  float* out = (float*)d_out;

  ushort_t* xb     = (ushort_t*)d_ws;                  // [8192,768]  bf16
  ushort_t* wqkvT  = xb + (size_t)NTOK * DIMD;         // [2304,768]  bf16 (T)
  ushort_t* wprojT = wqkvT + (size_t)QKVD * DIMD;      // [768,768]   bf16 (T)
  ushort_t* qkv    = wprojT + (size_t)DIMD * DIMD;     // [8192,2304] bf16
  ushort_t* att    = qkv + (size_t)NTOK * QKVD;        // [8192,768]  bf16

  cvt_bf16<<<(NTOK * DIMD / 8 + 255) / 256, 256, 0, stream>>>(x, xb, NTOK * DIMD / 8);
  tcvt_bf16<<<dim3(QKVD / 32, DIMD / 32), 256, 0, stream>>>(w_qkv, wqkvT, DIMD, QKVD);
  tcvt_bf16<<<dim3(DIMD / 32, DIMD / 32), 256, 0, stream>>>(w_proj, wprojT, DIMD, DIMD);

  gemm_bf16<1><<<dim3(QKVD / 128, NTOK / 128), 256, 0, stream>>>(
      xb, wqkvT, nullptr, qkv, NTOK, QKVD, DIMD);

  attn_mfma<<<dim3(BATCH * HEADS, SEQ / QPB), 256, 0, stream>>>(qkv, att);

  gemm_bf16<0><<<dim3(DIMD / 128, NTOK / 128), 256, 0, stream>>>(
      att, wprojT, b_proj, out, NTOK, DIMD, DIMD);
}